// Round 11
// baseline (205.430 us; speedup 1.0000x reference)
//
#include <hip/hip_runtime.h>

#define NN 50000
#define NE 800000
#define KD 256
#define CD 128
#define NB 196            // scan blocks: 196*256 = 50176 >= NN
#define GEMM_BLOCKS 782   // (NN+63)/64
#define HIST_BLOCKS 3125  // (NE+255)/256, 1 edge/thread
#define META_BLOCKS 782   // 4 edges/thread

typedef __attribute__((ext_vector_type(8))) short short8;
typedef __attribute__((ext_vector_type(4))) float floatx4;
typedef __attribute__((ext_vector_type(2))) float floatx2;

__device__ inline unsigned short f2bf(float f) {
    unsigned u = __float_as_uint(f);
    unsigned r = (u + 0x7FFFu + ((u >> 16) & 1u)) >> 16;   // RNE
    return (unsigned short)r;
}
__device__ inline float bf2f_lo(unsigned u) { return __uint_as_float(u << 16); }
__device__ inline float bf2f_hi(unsigned u) { return __uint_as_float(u & 0xFFFF0000u); }

// ===== L1: hist (blocks < HIST_BLOCKS) + W transpose + scan-state zero =====
// ATTRIBUTION SPLIT: hist isolated from the GEMM so the profile shows each
// phase's true cost (fused was 43-48us invariant to 4 structural changes —
// models of both sub-phases failed; measure before optimizing further).
// hist: packed {count:8 | sum(ew) Q6.18:24}, 4 shadow copies, copy = hblk&3
// == (e>>8)&3 (matches meta_write). packedAll zeroed by host-side memset.
__global__ __launch_bounds__(256) void hist_prep(
        const float* __restrict__ W, unsigned short* __restrict__ Wt,
        const int* __restrict__ col, const float* __restrict__ ew,
        unsigned* __restrict__ packedAll, unsigned short* __restrict__ rank,
        unsigned long long* __restrict__ state) {
    __shared__ unsigned short t[32][33];
    if (blockIdx.x < HIST_BLOCKS) {
        const int e = blockIdx.x * 256 + threadIdx.x;
        if (e < NE) {
            unsigned* packed = packedAll + (size_t)(blockIdx.x & 3) * NN;
            unsigned p = (1u << 24) + (unsigned)(ew[e] * 262144.0f);
            unsigned old = atomicAdd(&packed[col[e]], p);
            rank[e] = (unsigned short)(old >> 24);   // rank within copy
        }
        return;
    }
    const int b2 = blockIdx.x - HIST_BLOCKS;     // [0,32): 8 k-tiles x 4 n-tiles
    if (b2 == 0) {                               // zero lookback state (u64s)
        for (int i = threadIdx.x; i < NB * 8; i += 256) state[i] = 0ull;
    }
    const int bk = (b2 & 7) * 32;
    const int bn = (b2 >> 3) * 32;
    const int tx = threadIdx.x & 31;
    const int ty = threadIdx.x >> 5;
#pragma unroll
    for (int i = 0; i < 32; i += 8)
        t[ty + i][tx] = f2bf(W[(size_t)(bk + ty + i) * CD + bn + tx]);
    __syncthreads();
#pragma unroll
    for (int i = 0; i < 32; i += 8)
        Wt[(size_t)(bn + ty + i) * KD + bk + tx] = t[tx][ty + i];
}

// ===== L2: pure GEMM, h = bf16(x) @ Wt^T, 64 rows x 128 ch / block =====
// r9's hybrid form verbatim (bank-conflict-free): A direct-from-x in consume
// layout (no cross-block reuse), B staged via LDS in four 16KB quarters.
__global__ __launch_bounds__(256) void gemm(
        const float* __restrict__ x, const unsigned short* __restrict__ Wt,
        unsigned short* __restrict__ hb) {
    __shared__ unsigned short Bs[128][68];   // 17408 B; row stride 34 dwords

    const int tid  = threadIdx.x;
    const int wave = tid >> 6;
    const int lane = tid & 63;
    const int row0 = blockIdx.x * 64;
    const int m0   = wave * 16;
    const int lr   = lane & 15;
    const int quad = lane >> 4;

    const int grow_a = row0 + m0 + lr;           // A row this lane consumes
    const bool ok = grow_a < NN;
    const float* xp = x + (size_t)grow_a * KD + quad * 8;

    // Preload ALL A fragments (8 x 32B independent loads, front-loaded; their
    // latency hides under the first B staging).
    union { short8 v; unsigned short us[8]; } avs[8];
#pragma unroll
    for (int kt = 0; kt < 8; kt++) {
        if (ok) {
            const float4 f0 = *(const float4*)(xp + kt * 32);
            const float4 f1 = *(const float4*)(xp + kt * 32 + 4);
            avs[kt].us[0] = f2bf(f0.x); avs[kt].us[1] = f2bf(f0.y);
            avs[kt].us[2] = f2bf(f0.z); avs[kt].us[3] = f2bf(f0.w);
            avs[kt].us[4] = f2bf(f1.x); avs[kt].us[5] = f2bf(f1.y);
            avs[kt].us[6] = f2bf(f1.z); avs[kt].us[7] = f2bf(f1.w);
        } else {
            avs[kt].v = (short8){0,0,0,0,0,0,0,0};
        }
    }

    floatx4 acc[8];
#pragma unroll
    for (int nt = 0; nt < 8; nt++) acc[nt] = (floatx4){0.f, 0.f, 0.f, 0.f};

#pragma unroll
    for (int kq = 0; kq < 4; kq++) {             // four 64-k quarters
        if (kq) __syncthreads();                 // protect Bs overwrite
        // stage quarter: 128 rows x 64 k x 2B = 16KB; 4 rounds x 256thr x 16B
#pragma unroll
        for (int r8 = 0; r8 < 4; r8++) {
            const int idx  = r8 * 256 + tid;     // 1024 chunks of 8 bf16
            const int rown = idx >> 3;           // 8 chunks per 64-k row
            const int koff = (idx & 7) * 8;
            *(short8*)&Bs[rown][koff] =
                *(const short8*)(Wt + (size_t)rown * KD + kq * 64 + koff);
        }
        __syncthreads();
#pragma unroll
        for (int kt2 = 0; kt2 < 2; kt2++) {
            const int kt = kq * 2 + kt2;
            short8 b[8];
#pragma unroll
            for (int nt = 0; nt < 8; nt++)
                b[nt] = *(const short8*)&Bs[nt * 16 + lr][kt2 * 32 + quad * 8];
#pragma unroll
            for (int nt = 0; nt < 8; nt++)
                acc[nt] = __builtin_amdgcn_mfma_f32_16x16x32_bf16(
                              avs[kt].v, b[nt], acc[nt], 0, 0, 0);
        }
    }

#pragma unroll
    for (int i = 0; i < 4; i++) {
        const int grow = row0 + m0 + quad * 4 + i;
        if (grow < NN) {
            unsigned short* hp = hb + (size_t)grow * CD + lr;
#pragma unroll
            for (int nt = 0; nt < 8; nt++)
                hp[nt * 16] = f2bf(acc[nt][i]);
        }
    }
}

// ===== single-launch scan, WAVE-PARALLEL decoupled lookback =====
// state[b*8] u64 = {status:32 | value:32}; 0=invalid, 1=aggregate, 2=prefix.
// Flag+value travel in one relaxed agent-scope word (cross-XCD-safe pattern).
__global__ __launch_bounds__(256) void scan_lookback(
        const unsigned* __restrict__ packedAll,
        unsigned long long* __restrict__ state,
        int* __restrict__ start, int4* __restrict__ base4,
        float* __restrict__ dinv) {
    __shared__ int sm[256];
    __shared__ int sbase;
    const int t = threadIdx.x;
    const int b = blockIdx.x;
    const int g = b * 256 + t;

    int cc[4] = {0, 0, 0, 0};
    unsigned lowsum = 0;
    int v = 0;
    if (g < NN) {
#pragma unroll
        for (int c = 0; c < 4; c++) {
            unsigned p = packedAll[(size_t)c * NN + g];
            cc[c] = (int)(p >> 24);
            lowsum += p & 0xFFFFFFu;
            v += cc[c];
        }
    }
    sm[t] = v;
    __syncthreads();
#pragma unroll
    for (int off = 1; off < 256; off <<= 1) {
        int u = (t >= off) ? sm[t - off] : 0;
        __syncthreads();
        sm[t] += u;
        __syncthreads();
    }
    const int incl = sm[t];          // inclusive prefix within block
    const int total = sm[255];

    if (t == 0) {                    // publish immediately (b0: full prefix)
        unsigned long long post =
            ((b == 0 ? 2ull : 1ull) << 32) | (unsigned)total;
        __hip_atomic_store(&state[(size_t)b * 8], post,
                           __ATOMIC_RELAXED, __HIP_MEMORY_SCOPE_AGENT);
        if (b == 0) sbase = 0;
    }
    if (b > 0 && t < 64) {
        long long run = 0;
        int i = b - 1;
        while (true) {
            const int idx = i - t;
            unsigned long long s = (idx >= 0)
                ? __hip_atomic_load(&state[(size_t)idx * 8],
                                    __ATOMIC_RELAXED, __HIP_MEMORY_SCOPE_AGENT)
                : (2ull << 32);                      // virtual prefix-0 at -1
            const unsigned st = (unsigned)(s >> 32);
            const unsigned long long b0m = __ballot(st == 0u);
            const unsigned long long b2m = __ballot(st == 2u);
            if (b2m) {
                const int L = __ffsll((long long)b2m) - 1;   // nearest prefix
                const unsigned long long below =
                    (L == 63) ? ~0ull : ((1ull << (L + 1)) - 1ull);
                if (b0m & below) { __builtin_amdgcn_s_sleep(1); continue; }
                unsigned val = (t <= L) ? (unsigned)s : 0u;
#pragma unroll
                for (int o = 32; o; o >>= 1) val += __shfl_xor(val, o);
                run += val;
                break;
            } else if (b0m) {
                const int L0 = __ffsll((long long)b0m) - 1;  // consume < L0
                unsigned val = (t < L0) ? (unsigned)s : 0u;
#pragma unroll
                for (int o = 32; o; o >>= 1) val += __shfl_xor(val, o);
                run += val;
                i -= L0;
                if (L0 == 0) __builtin_amdgcn_s_sleep(1);
            } else {                                         // all aggregates
                unsigned val = (unsigned)s;
#pragma unroll
                for (int o = 32; o; o >>= 1) val += __shfl_xor(val, o);
                run += val;
                i -= 64;
            }
        }
        if (t == 0) {
            __hip_atomic_store(&state[(size_t)b * 8],
                               (2ull << 32) | (unsigned)(run + total),
                               __ATOMIC_RELAXED, __HIP_MEMORY_SCOPE_AGENT);
            sbase = (int)run;
        }
    }
    __syncthreads();
    const int base = sbase;

    if (g < NN) {
        const int s = base + (incl - v);
        start[g] = s;
        base4[g] = make_int4(s, s + cc[0], s + cc[0] + cc[1], s + cc[0] + cc[1] + cc[2]);
        float degs = (float)lowsum * (1.0f / 262144.0f);
        dinv[g] = rsqrtf(1.0f + degs);
    }
    if (g == 0) start[NN] = NE;
}

// -------- atomic-free CSR placement, 4 edges/thread vectorized:
// meta[base4[col][copy]+rank] = {bf16 dinv[row]*ew | u16 row}
__global__ __launch_bounds__(256) void meta_write(const int* __restrict__ row,
                                                  const int* __restrict__ col,
                                                  const float* __restrict__ ew,
                                                  const unsigned short* __restrict__ rank,
                                                  const int4* __restrict__ base4,
                                                  const float* __restrict__ dinv,
                                                  unsigned* __restrict__ meta) {
    const int e0 = (blockIdx.x * 256 + threadIdx.x) * 4;
    if (e0 >= NE) return;
    const int4 c4 = *(const int4*)(col + e0);
    const int4 r4 = *(const int4*)(row + e0);
    const float4 w4 = *(const float4*)(ew + e0);
    const ushort4 k4 = *(const ushort4*)(rank + e0);
    const int cs[4] = {c4.x, c4.y, c4.z, c4.w};
    const int rs[4] = {r4.x, r4.y, r4.z, r4.w};
    const float wsv[4] = {w4.x, w4.y, w4.z, w4.w};
    const unsigned short ks[4] = {k4.x, k4.y, k4.z, k4.w};
#pragma unroll
    for (int j = 0; j < 4; j++) {
        const int e = e0 + j;
        const int copy = (e >> 8) & 3;          // wave-uniform (256-edge runs)
        const int4 b4 = base4[cs[j]];
        const int base = (copy == 0) ? b4.x : (copy == 1) ? b4.y
                       : (copy == 2) ? b4.z : b4.w;
        const unsigned short wbf = f2bf(dinv[rs[j]] * wsv[j]);
        meta[base + ks[j]] = ((unsigned)wbf << 16) | (unsigned)rs[j];
    }
}

// ---------- pull aggregation: one wave per node, bf16 h, 8-way ILP, fused
// epilogue. meta is streamed nontemporally (no reuse) to keep L2 for hb.
__global__ __launch_bounds__(256) void aggregate(const int* __restrict__ start,
                                                 const unsigned* __restrict__ meta,
                                                 const unsigned short* __restrict__ hb,
                                                 const float* __restrict__ dinv,
                                                 const float* __restrict__ bias,
                                                 const float* __restrict__ alpha,
                                                 float* __restrict__ out) {
    int n = blockIdx.x * 4 + (threadIdx.x >> 6);
    if (n >= NN) return;
    n = __builtin_amdgcn_readfirstlane(n);
    const int lane = threadIdx.x & 63;
    const int s = __builtin_amdgcn_readfirstlane(start[n]);
    const int e = __builtin_amdgcn_readfirstlane(start[n + 1]);

    float A0[8], A1[8];
#pragma unroll
    for (int j = 0; j < 8; j++) { A0[j] = 0.f; A1[j] = 0.f; }

    int i = s;
    for (; i + 8 <= e; i += 8) {
        unsigned m[8], u[8];
#pragma unroll
        for (int j = 0; j < 8; j++) m[j] = __builtin_nontemporal_load(meta + i + j);
#pragma unroll
        for (int j = 0; j < 8; j++)
            u[j] = *(const unsigned*)(hb + (size_t)(m[j] & 0xFFFFu) * CD + lane * 2);
#pragma unroll
        for (int j = 0; j < 8; j++) {
            float w = __uint_as_float(m[j] & 0xFFFF0000u);
            A0[j] = fmaf(w, bf2f_lo(u[j]), A0[j]);
            A1[j] = fmaf(w, bf2f_hi(u[j]), A1[j]);
        }
    }
    for (; i < e; i++) {
        unsigned m = __builtin_nontemporal_load(meta + i);
        unsigned u = *(const unsigned*)(hb + (size_t)(m & 0xFFFFu) * CD + lane * 2);
        float w = __uint_as_float(m & 0xFFFF0000u);
        A0[0] = fmaf(w, bf2f_lo(u), A0[0]);
        A1[0] = fmaf(w, bf2f_hi(u), A1[0]);
    }
#pragma unroll
    for (int j = 1; j < 8; j++) { A0[0] += A0[j]; A1[0] += A1[j]; }

    const float dc = dinv[n];
    unsigned us = *(const unsigned*)(hb + (size_t)n * CD + lane * 2);
    const int ch = lane * 2;
    float o0 = dc * A0[0] + dc * dc * bf2f_lo(us) + bias[ch];
    float o1 = dc * A1[0] + dc * dc * bf2f_hi(us) + bias[ch + 1];
    o0 = o0 >= 0.f ? o0 : alpha[ch] * o0;
    o1 = o1 >= 0.f ? o1 : alpha[ch + 1] * o1;
    floatx2 o; o.x = o0; o.y = o1;
    __builtin_nontemporal_store(o, (floatx2*)(out + (size_t)n * CD + ch));
}

extern "C" void kernel_launch(void* const* d_in, const int* in_sizes, int n_in,
                              void* d_out, int out_size, void* d_ws, size_t ws_size,
                              hipStream_t stream) {
    const float* x     = (const float*)d_in[0];
    const int*   eidx  = (const int*)d_in[1];   // [2, NE]
    const float* ew    = (const float*)d_in[2];
    const float* Wm    = (const float*)d_in[3];
    const float* bias  = (const float*)d_in[4];
    const float* alpha = (const float*)d_in[5];
    const int* row = eidx;
    const int* col = eidx + NE;

    float* out = (float*)d_out;

    // workspace layout (bytes), no overlaps:
    char* ws = (char*)d_ws;
    unsigned* packedAll = (unsigned*)(ws);                   // 4*NN u32   [0, 800000)
    unsigned long long* state = (unsigned long long*)(ws + 800000); // NB*8 u64 [800000, 812544)
    int*   start    = (int*)(ws + 812544);                   // NN+1 int   [812544, 1012548)
    float* dinv     = (float*)(ws + 1012608);                // NN f32     [1012608, 1212608)
    unsigned short* rank = (unsigned short*)(ws + 1212608);  // NE u16     [1212608, 2812608)
    int4*  base4    = (int4*)(ws + 2812608);                 // NN int4    [2812608, 3612608)
    unsigned* meta  = (unsigned*)(ws + 3612608);             // NE u32     [3612608, 6812608)
    unsigned short* Wt = (unsigned short*)(ws + 6812608);    // 128*256 bf16 [6812608, 6878144)
    unsigned short* hb = (unsigned short*)(ws + 6878144);    // 50176*128 bf16 [6878144, 19723200)

    hipMemsetAsync(packedAll, 0, 800000, stream);            // hist shadows
    hist_prep    <<<HIST_BLOCKS + 32, 256, 0, stream>>>(Wm, Wt, col, ew,
                                                        packedAll, rank, state);
    gemm         <<<GEMM_BLOCKS, 256, 0, stream>>>(x, Wt, hb);
    scan_lookback<<<NB, 256, 0, stream>>>(packedAll, state, start, base4, dinv);
    meta_write   <<<META_BLOCKS, 256, 0, stream>>>(row, col, ew, rank, base4, dinv, meta);
    aggregate    <<<(NN + 3) / 4, 256, 0, stream>>>(start, meta, hb, dinv, bias, alpha, out);
}